// Round 6
// baseline (419.510 us; speedup 1.0000x reference)
//
#include <hip/hip_runtime.h>
#include <hip/hip_cooperative_groups.h>
#include <stdint.h>
#include <math.h>

namespace cg = cooperative_groups;

#define HH 256
#define WW 256
#define BATCH 16
#define HP 257            // pooled field is 257x257
#define SROW 264          // padded row stride
#define SH 259            // padded rows (1 zero row top/bottom)
#define SBP (SH*SROW)     // per-batch padded s size = 68376 floats
#define NPIX (HP*HP)      // 66049
#define NBLK 512          // 2 blocks/CU on 256 CUs — safely under coop co-residency limit

__device__ __forceinline__ float leaky(float v){ return v >= 0.f ? v : 0.01f*v; }

__device__ __forceinline__ unsigned fkey(float f){
    unsigned u = __float_as_uint(f);
    return (u & 0x80000000u) ? ~u : (u | 0x80000000u);
}
__device__ __forceinline__ float funkey(unsigned k){
    return (k & 0x80000000u) ? __uint_as_float(k ^ 0x80000000u) : __uint_as_float(~k);
}

// group k (0..3) channel-0 offset; channel 1 uses the negation.
__device__ __forceinline__ void group_off(int k, int& dh, int& dw){
    dh = (k == 3) ? 0 : -1;
    dw = (k == 3) ? 1 : (k - 1);
}

// ============================ cooperative mega-kernel ============================
__global__ __launch_bounds__(256) void mega(
        const float* __restrict__ x, const float* __restrict__ cl, const float* __restrict__ chp,
        const float* __restrict__ we, const float* __restrict__ be,
        const float* __restrict__ wc, const float* __restrict__ bc,
        const float* __restrict__ wf, const float* __restrict__ bf,
        float* __restrict__ out,
        float* __restrict__ s, unsigned* __restrict__ mnk, unsigned* __restrict__ mxk,
        float* __restrict__ hist, float* __restrict__ hsm, float* __restrict__ stats,
        float* __restrict__ w9g){
    cg::grid_group grid = cg::this_grid();
    __shared__ __align__(16) float smem[8192];   // 32 KB
    int tid = threadIdx.x, bid = blockIdx.x;
    int wv = tid >> 6, lane = tid & 63;

    // ================ P1: pool -> s (zero-padded); block 0 inits atomics/hist ================
    if (bid == 0){
        if (tid < 128){ mnk[tid] = 0xFFFFFFFFu; mxk[tid] = 0u; }
        for (int t = tid; t < 4096; t += 256) hist[t] = 0.f;
    }
    for (int idx = bid*256 + tid; idx < BATCH*SBP; idx += NBLK*256){
        int b = idx / SBP;
        int r = idx % SBP;
        int ph = r / SROW, pw = r % SROW;
        int h = ph - 1, w = pw - 1;
        float val = 0.f;
        if ((unsigned)h < (unsigned)HP && (unsigned)w < (unsigned)HP){
            const float* xb = x + (size_t)b*3*HH*WW;
            float acc = 0.f;
            #pragma unroll
            for (int dy=-1; dy<=0; ++dy){
                int i = h+dy; if ((unsigned)i >= HH) continue;
                #pragma unroll
                for (int dx=-1; dx<=0; ++dx){
                    int j = w+dx; if ((unsigned)j >= WW) continue;
                    int o = i*WW + j;
                    acc += xb[o] + xb[HH*WW + o] + xb[2*HH*WW + o];
                }
            }
            val = acc * 0.25f;
        }
        s[idx] = val;
    }
    grid.sync();

    // ================ P2: min/max per (batch, group, ch); per-pixel all groups ================
    {
        int b = bid >> 5, chunk = bid & 31;    // 32 blocks per batch
        const float* sp = s + (size_t)b*SBP + SROW + 1;
        float mn[8], mx[8];
        #pragma unroll
        for (int q=0;q<8;q++){ mn[q]=INFINITY; mx[q]=-INFINITY; }
        for (int idx = chunk*256 + tid; idx < NPIX; idx += 32*256){
            int h = idx / HP, w = idx - h*HP;
            const float* p = sp + h*SROW + w;
            float c = p[0];
            float n0 = p[-SROW-1], n1 = p[-SROW], n2 = p[-SROW+1], n3 = p[1];
            float o0 = p[ SROW+1], o1 = p[ SROW], o2 = p[ SROW-1], o3 = p[-1];
            float v0=c-n0, v1=c-o0, v2=c-n1, v3=c-o1, v4=c-n2, v5=c-o2, v6=c-n3, v7=c-o3;
            mn[0]=fminf(mn[0],v0); mx[0]=fmaxf(mx[0],v0);
            mn[1]=fminf(mn[1],v1); mx[1]=fmaxf(mx[1],v1);
            mn[2]=fminf(mn[2],v2); mx[2]=fmaxf(mx[2],v2);
            mn[3]=fminf(mn[3],v3); mx[3]=fmaxf(mx[3],v3);
            mn[4]=fminf(mn[4],v4); mx[4]=fmaxf(mx[4],v4);
            mn[5]=fminf(mn[5],v5); mx[5]=fmaxf(mx[5],v5);
            mn[6]=fminf(mn[6],v6); mx[6]=fmaxf(mx[6],v6);
            mn[7]=fminf(mn[7],v7); mx[7]=fmaxf(mx[7],v7);
        }
        #pragma unroll
        for (int off=32; off; off>>=1){
            #pragma unroll
            for (int q=0;q<8;q++){
                mn[q] = fminf(mn[q], __shfl_down(mn[q], off));
                mx[q] = fmaxf(mx[q], __shfl_down(mx[q], off));
            }
        }
        float* redmn = smem;        // [4][8]
        float* redmx = smem + 32;   // [4][8]
        if (lane == 0){
            #pragma unroll
            for (int q=0;q<8;q++){ redmn[wv*8+q]=mn[q]; redmx[wv*8+q]=mx[q]; }
        }
        __syncthreads();
        if (tid < 8){
            float a  = fminf(fminf(redmn[tid],redmn[8+tid]), fminf(redmn[16+tid],redmn[24+tid]));
            float bb = fmaxf(fmaxf(redmx[tid],redmx[8+tid]), fmaxf(redmx[16+tid],redmx[24+tid]));
            float lo = cl[0], hi = chp[0];
            int g = b*4 + (tid>>1), ch = tid&1;
            atomicMin(&mnk[g*2+ch], fkey(fminf(fmaxf(a,  lo), hi)));
            atomicMax(&mxk[g*2+ch], fkey(fminf(fmaxf(bb, lo), hi)));
        }
        __syncthreads();
    }
    grid.sync();

    // ================ P3: joint histogram; wave wv = group wv, 32 replicas ================
    {
        float* lh = smem;   // [4][64][32]
        for (int t = tid; t < 4*64*32; t += 256) lh[t] = 0.f;
        __syncthreads();
        int b = bid >> 5, chunk = bid & 31;
        int g = b*4 + wv;
        float lo = cl[0], hi = chp[0];
        float mn0 = funkey(mnk[g*2+0]), mx0 = funkey(mxk[g*2+0]);
        float mn1 = funkey(mnk[g*2+1]), mx1 = funkey(mxk[g*2+1]);
        float cd0 = (mx0-mn0)*0.125f;
        float cd1 = (mx1-mn1)*0.125f;
        float m0[9], m1[9];
        #pragma unroll
        for (int i=0;i<9;i++){
            m0[i] = __fadd_rn(__fmul_rn((float)i, cd0), mn0);   // match ref: mul then add, no fma
            m1[i] = __fadd_rn(__fmul_rn((float)i, cd1), mn1);
        }
        int dh, dw; group_off(wv, dh, dw);
        int doff = dh*SROW + dw;
        const float* sp = s + (size_t)b*SBP + SROW + 1;
        float* lhg = lh + wv*2048 + (lane & 31);
        for (int idx = chunk*64 + lane; idx < NPIX; idx += 32*64){
            int h = idx / HP, w = idx - h*HP;
            const float* p = sp + h*SROW + w;
            float c = p[0];
            float v0 = fminf(fmaxf(c - p[doff],  lo), hi);
            float v1 = fminf(fmaxf(c - p[-doff], lo), hi);
            unsigned b0=0, b1=0;
            #pragma unroll
            for (int i=0;i<8;i++){
                b0 |= (v0>=m0[i] && v0<=m0[i+1]) ? (1u<<i) : 0u;  // boundary values hit 2 bins, like ref
                b1 |= (v1>=m1[i] && v1<=m1[i+1]) ? (1u<<i) : 0u;
            }
            float pr = v0*v1;
            unsigned bb0=b0;
            while (bb0){
                int i = __ffs(bb0)-1; bb0 &= bb0-1;
                unsigned bb1=b1;
                while (bb1){
                    int j = __ffs(bb1)-1; bb1 &= bb1-1;
                    atomicAdd(&lhg[(i*8+j)*32], pr);
                }
            }
        }
        __syncthreads();
        float acc = 0.f;
        #pragma unroll
        for (int r=0;r<32;r++) acc += lh[(wv*64 + lane)*32 + ((lane + r)&31)];
        atomicAdd(&hist[g*64 + lane], acc);
        __syncthreads();
    }
    grid.sync();

    // ================ P4: blocks 0..63: expand+leaky -> hsm, weighted LN stats ================
    if (bid < 64){
        float* hloc = smem;          // [3584]
        float* sred = smem + 3584;   // [4]
        int g = bid;
        float ps = 0.f;
        for (int t=tid; t<4096; t+=256) ps += hist[t];
        #pragma unroll
        for (int off=32; off; off>>=1) ps += __shfl_down(ps, off);
        if (lane==0) sred[wv] = ps;
        __syncthreads();
        float S = sred[0]+sred[1]+sred[2]+sred[3];

        float mn0 = funkey(mnk[g*2+0]), mx0 = funkey(mxk[g*2+0]);
        float mn1 = funkey(mnk[g*2+1]), mx1 = funkey(mxk[g*2+1]);
        float lvl0 = __fadd_rn(__fmul_rn(1.0f,(mx0-mn0)*0.125f), mn0);   // measure[:,1,0]
        float lvl1 = __fadd_rn(__fmul_rn(1.0f,(mx1-mn1)*0.125f), mn1);

        for (int e=tid; e<3584; e+=256){
            int ij = e/56, o = e%56;
            int i = ij>>3, j = ij&7;
            float f0 = __fmul_rn((float)(i+1), lvl0);
            float f1 = __fmul_rn((float)(j+1), lvl1);
            float f2 = hist[g*64+ij] / S;
            float a = f0*we[o*3+0] + f1*we[o*3+1] + f2*we[o*3+2] + be[o];
            a = leaky(a);
            hloc[e] = a;
            hsm[(size_t)g*3584 + e] = a;
        }
        __syncthreads();

        float pm = 0.f;
        for (int e=tid; e<3584; e+=256){
            int o = e%56;
            int lo_ = (32*o+6)/7, hi_ = (32*o+31)/7;
            pm += hloc[e] * (float)(4*(hi_-lo_+1));
        }
        #pragma unroll
        for (int off=32; off; off>>=1) pm += __shfl_down(pm, off);
        if (lane==0) sred[wv]=pm;
        __syncthreads();
        float mean = (sred[0]+sred[1]+sred[2]+sred[3]) * (1.0f/65536.0f);
        __syncthreads();
        float pv = 0.f;
        for (int e=tid; e<3584; e+=256){
            int o = e%56;
            int lo_ = (32*o+6)/7, hi_ = (32*o+31)/7;
            float d = hloc[e]-mean;
            pv += d*d * (float)(4*(hi_-lo_+1));
        }
        #pragma unroll
        for (int off=32; off; off>>=1) pv += __shfl_down(pv, off);
        if (lane==0) sred[wv]=pv;
        __syncthreads();
        float var = (sred[0]+sred[1]+sred[2]+sred[3]) * (1.0f/65536.0f);
        if (tid==0){
            stats[g*2+0] = mean;
            stats[g*2+1] = 1.0f / sqrtf(var + 1e-5f);
        }
    }
    grid.sync();

    // ================ P5: LN + w_conv + leaky + fold w_final -> w9[b][r][9][56] ================
    {
        float* wfl = smem;   // [144]
        if (tid < 144) wfl[tid] = wf[tid];
        __syncthreads();
        for (int idx = bid*256 + tid; idx < 16*64*56; idx += NBLK*256){
            int sxc = idx % 56;
            int r = (idx/56) & 63;
            int b = idx / (56*64);
            int e = r*56 + sxc;
            float hn[4];
            #pragma unroll
            for (int k=0;k<4;k++){
                int g = b*4+k;
                hn[k] = (hsm[(size_t)g*3584 + e] - stats[g*2]) * stats[g*2+1];
            }
            float w9v[9] = {0,0,0,0,0,0,0,0,0};
            #pragma unroll
            for (int c=0;c<16;c++){
                float hv = bc[c];
                #pragma unroll
                for (int k=0;k<4;k++) hv += wc[c*4+k]*hn[k];
                hv = leaky(hv);
                #pragma unroll
                for (int t=0;t<9;t++) w9v[t] += wfl[c*9+t]*hv;
            }
            float* dst = w9g + (((size_t)b*64 + r)*9)*56 + sxc;
            #pragma unroll
            for (int t=0;t<9;t++) dst[t*56] = w9v[t];
        }
    }
    grid.sync();

    // ================ P6: out[b,y,x]; 8 rows per block ================
    {
        int x_ = tid;
        float bias = bf[0];
        int sxm = ((x_-1)*7) >> 5;
        int sx0 = (x_*7) >> 5;
        int sxp = ((x_+1)*7) >> 5;
        #pragma unroll
        for (int t8=0; t8<8; ++t8){
            int task = bid*8 + t8;        // 0..4095
            int y = task & 255;
            int b = task >> 8;
            const float* wb = w9g + (size_t)b*64*9*56;
            float acc = bias;
            #pragma unroll
            for (int dy=0; dy<3; ++dy){
                int yy = y + dy - 1;
                if ((unsigned)yy >= 256u) continue;
                const float* wr = wb + (((yy>>2)*9) + dy*3)*56;
                if (x_ >= 1)   acc += wr[0*56 + sxm];
                               acc += wr[1*56 + sx0];
                if (x_ <= 254) acc += wr[2*56 + sxp];
            }
            out[((size_t)(b*256 + y))*256 + x_] = leaky(acc);
        }
    }
}

// ============================ fallback: round-4 six-kernel path ============================
__global__ __launch_bounds__(256) void k1_pool(const float* __restrict__ x, float* __restrict__ s,
                                               unsigned* __restrict__ mnk, unsigned* __restrict__ mxk,
                                               float* __restrict__ hist){
    if (blockIdx.x == 0){
        if (threadIdx.x < 128){ mnk[threadIdx.x] = 0xFFFFFFFFu; mxk[threadIdx.x] = 0u; }
        for (int t = threadIdx.x; t < 4096; t += 256) hist[t] = 0.f;
    }
    int idx = blockIdx.x*256 + threadIdx.x;
    if (idx >= BATCH*SBP) return;
    int b = idx / SBP;
    int r = idx % SBP;
    int ph = r / SROW, pw = r % SROW;
    int h = ph - 1, w = pw - 1;
    float val = 0.f;
    if ((unsigned)h < (unsigned)HP && (unsigned)w < (unsigned)HP){
        const float* xb = x + (size_t)b*3*HH*WW;
        float acc = 0.f;
        #pragma unroll
        for (int dy=-1; dy<=0; ++dy){
            int i = h+dy; if ((unsigned)i >= HH) continue;
            #pragma unroll
            for (int dx=-1; dx<=0; ++dx){
                int j = w+dx; if ((unsigned)j >= WW) continue;
                int o = i*WW + j;
                acc += xb[o] + xb[HH*WW + o] + xb[2*HH*WW + o];
            }
        }
        val = acc * 0.25f;
    }
    s[idx] = val;
}

__global__ __launch_bounds__(256) void k2_minmax(const float* __restrict__ s, const float* __restrict__ cl,
                                                 const float* __restrict__ chp,
                                                 unsigned* __restrict__ mnk, unsigned* __restrict__ mxk){
    int b = blockIdx.y;
    int wv = threadIdx.x >> 6, lane = threadIdx.x & 63;
    int dh, dw; group_off(wv, dh, dw);
    int doff = dh*SROW + dw;
    const float* sp = s + (size_t)b*SBP + SROW + 1;
    float mn0=INFINITY, mx0=-INFINITY, mn1=INFINITY, mx1=-INFINITY;
    for (int idx = blockIdx.x*64 + lane; idx < NPIX; idx += gridDim.x*64){
        int h = idx / HP, w = idx - h*HP;
        const float* p = sp + h*SROW + w;
        float c = p[0];
        float v0 = c - p[doff];
        float v1 = c - p[-doff];
        mn0 = fminf(mn0,v0); mx0 = fmaxf(mx0,v0);
        mn1 = fminf(mn1,v1); mx1 = fmaxf(mx1,v1);
    }
    #pragma unroll
    for (int off=32; off; off>>=1){
        mn0 = fminf(mn0, __shfl_down(mn0, off));
        mx0 = fmaxf(mx0, __shfl_down(mx0, off));
        mn1 = fminf(mn1, __shfl_down(mn1, off));
        mx1 = fmaxf(mx1, __shfl_down(mx1, off));
    }
    if (lane == 0){
        float lo = cl[0], hi = chp[0];
        int g = b*4 + wv;
        atomicMin(&mnk[g*2+0], fkey(fminf(fmaxf(mn0, lo), hi)));
        atomicMax(&mxk[g*2+0], fkey(fminf(fmaxf(mx0, lo), hi)));
        atomicMin(&mnk[g*2+1], fkey(fminf(fmaxf(mn1, lo), hi)));
        atomicMax(&mxk[g*2+1], fkey(fminf(fmaxf(mx1, lo), hi)));
    }
}

__global__ __launch_bounds__(256) void k3_hist(const float* __restrict__ s, const float* __restrict__ cl,
                                               const float* __restrict__ chp,
                                               const unsigned* __restrict__ mnk, const unsigned* __restrict__ mxk,
                                               float* __restrict__ hist){
    __shared__ float lh[4*64*32];
    int b = blockIdx.y;
    int wv = threadIdx.x >> 6, lane = threadIdx.x & 63;
    for (int t = threadIdx.x; t < 4*64*32; t += 256) lh[t] = 0.f;
    __syncthreads();
    int g = b*4 + wv;
    float lo = cl[0], hi = chp[0];
    float mn0 = funkey(mnk[g*2+0]), mx0 = funkey(mxk[g*2+0]);
    float mn1 = funkey(mnk[g*2+1]), mx1 = funkey(mxk[g*2+1]);
    float cd0 = (mx0-mn0)*0.125f;
    float cd1 = (mx1-mn1)*0.125f;
    float m0[9], m1[9];
    #pragma unroll
    for (int i=0;i<9;i++){
        m0[i] = __fadd_rn(__fmul_rn((float)i, cd0), mn0);
        m1[i] = __fadd_rn(__fmul_rn((float)i, cd1), mn1);
    }
    int dh, dw; group_off(wv, dh, dw);
    int doff = dh*SROW + dw;
    const float* sp = s + (size_t)b*SBP + SROW + 1;
    float* lhg = lh + wv*2048 + (lane & 31);
    for (int idx = blockIdx.x*64 + lane; idx < NPIX; idx += gridDim.x*64){
        int h = idx / HP, w = idx - h*HP;
        const float* p = sp + h*SROW + w;
        float c = p[0];
        float v0 = fminf(fmaxf(c - p[doff],  lo), hi);
        float v1 = fminf(fmaxf(c - p[-doff], lo), hi);
        unsigned b0=0, b1=0;
        #pragma unroll
        for (int i=0;i<8;i++){
            b0 |= (v0>=m0[i] && v0<=m0[i+1]) ? (1u<<i) : 0u;
            b1 |= (v1>=m1[i] && v1<=m1[i+1]) ? (1u<<i) : 0u;
        }
        float pr = v0*v1;
        unsigned bb0=b0;
        while (bb0){
            int i = __ffs(bb0)-1; bb0 &= bb0-1;
            unsigned bb1=b1;
            while (bb1){
                int j = __ffs(bb1)-1; bb1 &= bb1-1;
                atomicAdd(&lhg[(i*8+j)*32], pr);
            }
        }
    }
    __syncthreads();
    float acc = 0.f;
    #pragma unroll
    for (int r=0;r<32;r++) acc += lh[(wv*64 + lane)*32 + ((lane + r)&31)];
    atomicAdd(&hist[g*64 + lane], acc);
}

__global__ __launch_bounds__(256) void k4a(const float* __restrict__ hist,
                    const unsigned* __restrict__ mnk, const unsigned* __restrict__ mxk,
                    const float* __restrict__ we, const float* __restrict__ be,
                    float* __restrict__ hsm, float* __restrict__ stats){
    __shared__ float hloc[3584];
    __shared__ float sred[4];
    int g = blockIdx.x;
    int tid = threadIdx.x;
    float ps = 0.f;
    for (int t=tid; t<4096; t+=256) ps += hist[t];
    #pragma unroll
    for (int off=32; off; off>>=1) ps += __shfl_down(ps, off);
    if ((tid&63)==0) sred[tid>>6] = ps;
    __syncthreads();
    float S = sred[0]+sred[1]+sred[2]+sred[3];

    float mn0 = funkey(mnk[g*2+0]), mx0 = funkey(mxk[g*2+0]);
    float mn1 = funkey(mnk[g*2+1]), mx1 = funkey(mxk[g*2+1]);
    float lvl0 = __fadd_rn(__fmul_rn(1.0f,(mx0-mn0)*0.125f), mn0);
    float lvl1 = __fadd_rn(__fmul_rn(1.0f,(mx1-mn1)*0.125f), mn1);

    for (int e=tid; e<3584; e+=256){
        int ij = e/56, o = e%56;
        int i = ij>>3, j = ij&7;
        float f0 = __fmul_rn((float)(i+1), lvl0);
        float f1 = __fmul_rn((float)(j+1), lvl1);
        float f2 = hist[g*64+ij] / S;
        float a = f0*we[o*3+0] + f1*we[o*3+1] + f2*we[o*3+2] + be[o];
        a = leaky(a);
        hloc[e] = a;
        hsm[(size_t)g*3584 + e] = a;
    }
    __syncthreads();

    float pm = 0.f;
    for (int e=tid; e<3584; e+=256){
        int o = e%56;
        int lo_ = (32*o+6)/7, hi_ = (32*o+31)/7;
        pm += hloc[e] * (float)(4*(hi_-lo_+1));
    }
    #pragma unroll
    for (int off=32; off; off>>=1) pm += __shfl_down(pm, off);
    if ((tid&63)==0) sred[tid>>6]=pm;
    __syncthreads();
    float mean = (sred[0]+sred[1]+sred[2]+sred[3]) * (1.0f/65536.0f);
    __syncthreads();
    float pv = 0.f;
    for (int e=tid; e<3584; e+=256){
        int o = e%56;
        int lo_ = (32*o+6)/7, hi_ = (32*o+31)/7;
        float d = hloc[e]-mean;
        pv += d*d * (float)(4*(hi_-lo_+1));
    }
    #pragma unroll
    for (int off=32; off; off>>=1) pv += __shfl_down(pv, off);
    if ((tid&63)==0) sred[tid>>6]=pv;
    __syncthreads();
    float var = (sred[0]+sred[1]+sred[2]+sred[3]) * (1.0f/65536.0f);
    if (tid==0){
        stats[g*2+0] = mean;
        stats[g*2+1] = 1.0f / sqrtf(var + 1e-5f);
    }
}

__global__ __launch_bounds__(256) void k4w(const float* __restrict__ hsm, const float* __restrict__ stats,
                                           const float* __restrict__ wc, const float* __restrict__ bc,
                                           const float* __restrict__ wf,
                                           float* __restrict__ w9g){
    __shared__ float wfl[144];
    if (threadIdx.x < 144) wfl[threadIdx.x] = wf[threadIdx.x];
    __syncthreads();
    int idx = blockIdx.x*256 + threadIdx.x;
    if (idx >= 16*64*56) return;
    int sxc = idx % 56;
    int r = (idx/56) & 63;
    int b = idx / (56*64);
    int e = r*56 + sxc;
    float hn[4];
    #pragma unroll
    for (int k=0;k<4;k++){
        int g = b*4+k;
        hn[k] = (hsm[(size_t)g*3584 + e] - stats[g*2]) * stats[g*2+1];
    }
    float w9v[9] = {0,0,0,0,0,0,0,0,0};
    #pragma unroll
    for (int c=0;c<16;c++){
        float hv = bc[c];
        #pragma unroll
        for (int k=0;k<4;k++) hv += wc[c*4+k]*hn[k];
        hv = leaky(hv);
        #pragma unroll
        for (int t=0;t<9;t++) w9v[t] += wfl[c*9+t]*hv;
    }
    float* dst = w9g + (((size_t)b*64 + r)*9)*56 + sxc;
    #pragma unroll
    for (int t=0;t<9;t++) dst[t*56] = w9v[t];
}

__global__ __launch_bounds__(256) void k5_out(const float* __restrict__ w9g, const float* __restrict__ bf,
                                              float* __restrict__ out){
    int x = threadIdx.x;
    int y = blockIdx.x & 255;
    int b = blockIdx.x >> 8;
    const float* wb = w9g + (size_t)b*64*9*56;
    float acc = bf[0];
    int sxm = ((x-1)*7) >> 5;
    int sx0 = (x*7) >> 5;
    int sxp = ((x+1)*7) >> 5;
    #pragma unroll
    for (int dy=0; dy<3; ++dy){
        int yy = y + dy - 1;
        if ((unsigned)yy >= 256u) continue;
        const float* wr = wb + (((yy>>2)*9) + dy*3)*56;
        if (x >= 1)   acc += wr[0*56 + sxm];
                      acc += wr[1*56 + sx0];
        if (x <= 254) acc += wr[2*56 + sxp];
    }
    out[((size_t)(b*256 + y))*256 + x] = leaky(acc);
}

extern "C" void kernel_launch(void* const* d_in, const int* in_sizes, int n_in,
                              void* d_out, int out_size, void* d_ws, size_t ws_size,
                              hipStream_t stream){
    const float* x  = (const float*)d_in[0];
    const float* cl = (const float*)d_in[1];
    const float* ch = (const float*)d_in[2];
    const float* we = (const float*)d_in[3];
    const float* be = (const float*)d_in[4];
    const float* wc = (const float*)d_in[5];
    const float* bc = (const float*)d_in[6];
    const float* wf = (const float*)d_in[7];
    const float* bf = (const float*)d_in[8];
    float* out = (float*)d_out;

    float* s = (float*)d_ws;                          // 16*SBP floats (zero-padded field)
    size_t off = (size_t)BATCH*SBP;
    unsigned* mnk = (unsigned*)(s + off); off += 128;
    unsigned* mxk = (unsigned*)(s + off); off += 128;
    float* hist = s + off; off += 4096;
    float* hsm  = s + off; off += 229376;
    float* stats= s + off; off += 128;
    float* w9g  = s + off; off += (size_t)16*64*9*56;

    void* args[] = { (void*)&x, (void*)&cl, (void*)&ch, (void*)&we, (void*)&be,
                     (void*)&wc, (void*)&bc, (void*)&wf, (void*)&bf, (void*)&out,
                     (void*)&s, (void*)&mnk, (void*)&mxk, (void*)&hist, (void*)&hsm,
                     (void*)&stats, (void*)&w9g };
    hipError_t err = hipLaunchCooperativeKernel((const void*)mega, dim3(NBLK), dim3(256),
                                                args, 0, stream);
    if (err != hipSuccess){
        // deterministic fallback: round-4 six-kernel path (known correct)
        k1_pool<<<(BATCH*SBP + 255)/256, 256, 0, stream>>>(x, s, mnk, mxk, hist);
        k2_minmax<<<dim3(64,16), 256, 0, stream>>>(s, cl, ch, mnk, mxk);
        k3_hist<<<dim3(64,16), 256, 0, stream>>>(s, cl, ch, mnk, mxk, hist);
        k4a<<<64, 256, 0, stream>>>(hist, mnk, mxk, we, be, hsm, stats);
        k4w<<<(16*64*56 + 255)/256, 256, 0, stream>>>(hsm, stats, wc, bc, wf, w9g);
        k5_out<<<16*256, 256, 0, stream>>>(w9g, bf, out);
    }
}

// Round 7
// 155.048 us; speedup vs baseline: 2.7057x; 2.7057x over previous
//
#include <hip/hip_runtime.h>
#include <stdint.h>
#include <math.h>

#define HH 256
#define WW 256
#define BATCH 16
#define HP 257            // pooled field is 257x257
#define SROW 264          // padded row stride
#define SH 259            // padded rows (1 zero row top/bottom)
#define SBP (SH*SROW)     // per-batch padded s size = 68376 floats
#define NPIX (HP*HP)      // 66049
#define TS 32             // K12 tile core
#define TH 9              // tiles per dim (9*32=288 >= 257)
#define NT (TH*TH)        // 81 tiles per batch

__device__ __forceinline__ float leaky(float v){ return v >= 0.f ? v : 0.01f*v; }

// group k (0..3) channel-0 offset; channel 1 uses the negation.
__device__ __forceinline__ void group_off(int k, int& dh, int& dw){
    dh = (k == 3) ? 0 : -1;
    dw = (k == 3) ? 1 : (k - 1);
}

// ---- K12: tiled pool -> s (+zero pad), 8-diff min/max partials per block ----
// blockIdx.x = b*NT + tile. Partial minmax of UNCLIPPED diffs (clip is monotone,
// consumers clamp after the final reduce). q = 2*group + channel.
__global__ __launch_bounds__(256) void k12(const float* __restrict__ x, float* __restrict__ s,
                                           float* __restrict__ pmn, float* __restrict__ pmx,
                                           float* __restrict__ hist){
    __shared__ float xs[35][36];
    __shared__ float sh[34][35];
    __shared__ float redmn[4][8], redmx[4][8];
    int blk = blockIdx.x, tid = threadIdx.x;
    int wv = tid >> 6, lane = tid & 63;
    int b = blk / NT, tile = blk % NT;
    int ty = tile / TH, tx = tile % TH;

    if (blk == 0){
        for (int t = tid; t < 4096; t += 256) hist[t] = 0.f;
    }
    // first 16 blocks zero the pad cells of batch blk (disjoint from all cores)
    if (blk < BATCH){
        float* sb = s + (size_t)blk*SBP;
        for (int t = tid; t < 2*SROW; t += 256){
            int rr = (t < SROW) ? 0 : 258; int cc = t % SROW;
            sb[rr*SROW + cc] = 0.f;
        }
        for (int t = tid; t < 257*7; t += 256){
            int rr = 1 + t/7, k = t%7;
            int cc = (k == 0) ? 0 : (257 + k);   // col 0 and cols 258..263
            sb[rr*SROW + cc] = 0.f;
        }
    }

    // stage channel-summed x over the region needed for s-halo: rows/cols ty*32-2 .. +32
    const float* xb = x + (size_t)b*3*HH*WW;
    int xr0 = ty*TS - 2, xc0 = tx*TS - 2;
    for (int t = tid; t < 35*35; t += 256){
        int i = t/35, j = t - i*35;
        int r = xr0 + i, c = xc0 + j;
        float v = 0.f;
        if ((unsigned)r < (unsigned)HH && (unsigned)c < (unsigned)WW){
            int o = r*WW + c;
            v = xb[o] + xb[HH*WW + o] + xb[2*HH*WW + o];
        }
        xs[i][j] = v;
    }
    __syncthreads();

    // s-halo 34x34: s(ty*32-1+i, tx*32-1+j); 0 outside [0,257)^2 (matches global pad)
    for (int t = tid; t < 34*34; t += 256){
        int i = t/34, j = t - i*34;
        int h = ty*TS - 1 + i, w = tx*TS - 1 + j;
        float v = 0.f;
        if ((unsigned)h < (unsigned)HP && (unsigned)w < (unsigned)HP)
            v = 0.25f*(xs[i][j] + xs[i][j+1] + xs[i+1][j] + xs[i+1][j+1]);
        sh[i][j] = v;
    }
    __syncthreads();

    float mn[8], mx[8];
    #pragma unroll
    for (int q=0;q<8;q++){ mn[q]=INFINITY; mx[q]=-INFINITY; }
    float* sb = s + (size_t)b*SBP;
    #pragma unroll
    for (int q4=0; q4<4; ++q4){
        int p = q4*256 + tid;
        int lr = p >> 5, lc = p & 31;
        int h = ty*TS + lr, w = tx*TS + lc;
        if (h < HP && w < HP){
            float c = sh[lr+1][lc+1];
            sb[(h+1)*SROW + (w+1)] = c;
            float d;
            d = c - sh[lr  ][lc  ]; mn[0]=fminf(mn[0],d); mx[0]=fmaxf(mx[0],d);  // g0 c0 (-1,-1)
            d = c - sh[lr+2][lc+2]; mn[1]=fminf(mn[1],d); mx[1]=fmaxf(mx[1],d);  // g0 c1 (+1,+1)
            d = c - sh[lr  ][lc+1]; mn[2]=fminf(mn[2],d); mx[2]=fmaxf(mx[2],d);  // g1 c0 (-1, 0)
            d = c - sh[lr+2][lc+1]; mn[3]=fminf(mn[3],d); mx[3]=fmaxf(mx[3],d);  // g1 c1 (+1, 0)
            d = c - sh[lr  ][lc+2]; mn[4]=fminf(mn[4],d); mx[4]=fmaxf(mx[4],d);  // g2 c0 (-1,+1)
            d = c - sh[lr+2][lc  ]; mn[5]=fminf(mn[5],d); mx[5]=fmaxf(mx[5],d);  // g2 c1 (+1,-1)
            d = c - sh[lr+1][lc+2]; mn[6]=fminf(mn[6],d); mx[6]=fmaxf(mx[6],d);  // g3 c0 ( 0,+1)
            d = c - sh[lr+1][lc  ]; mn[7]=fminf(mn[7],d); mx[7]=fmaxf(mx[7],d);  // g3 c1 ( 0,-1)
        }
    }
    #pragma unroll
    for (int off=32; off; off>>=1){
        #pragma unroll
        for (int q=0;q<8;q++){
            mn[q] = fminf(mn[q], __shfl_down(mn[q], off));
            mx[q] = fmaxf(mx[q], __shfl_down(mx[q], off));
        }
    }
    if (lane == 0){
        #pragma unroll
        for (int q=0;q<8;q++){ redmn[wv][q]=mn[q]; redmx[wv][q]=mx[q]; }
    }
    __syncthreads();
    if (tid < 8){
        pmn[(size_t)blk*8 + tid] = fminf(fminf(redmn[0][tid],redmn[1][tid]),
                                         fminf(redmn[2][tid],redmn[3][tid]));
        pmx[(size_t)blk*8 + tid] = fmaxf(fmaxf(redmx[0][tid],redmx[1][tid]),
                                         fmaxf(redmx[2][tid],redmx[3][tid]));
    }
}

// ---- K3: joint histogram. grid (32, BATCH); wave wv = group wv; 32 LDS replicas ----
__global__ __launch_bounds__(256) void k3_hist(const float* __restrict__ s, const float* __restrict__ cl,
                                               const float* __restrict__ chp,
                                               const float* __restrict__ pmn, const float* __restrict__ pmx,
                                               float* __restrict__ hist){
    __shared__ float lh[4*64*32];   // [group][bin][replica] = 32 KB
    int b = blockIdx.y;
    int wv = threadIdx.x >> 6, lane = threadIdx.x & 63;
    for (int t = threadIdx.x; t < 4*64*32; t += 256) lh[t] = 0.f;

    // reduce this batch+group's minmax partials (channels 2wv, 2wv+1)
    float mnA=INFINITY, mxA=-INFINITY, mnB=INFINITY, mxB=-INFINITY;
    for (int t = lane; t < NT; t += 64){
        const float* pn = pmn + ((size_t)(b*NT + t))*8;
        const float* px = pmx + ((size_t)(b*NT + t))*8;
        mnA = fminf(mnA, pn[2*wv]);   mxA = fmaxf(mxA, px[2*wv]);
        mnB = fminf(mnB, pn[2*wv+1]); mxB = fmaxf(mxB, px[2*wv+1]);
    }
    #pragma unroll
    for (int off=32; off; off>>=1){
        mnA = fminf(mnA, __shfl_down(mnA, off)); mxA = fmaxf(mxA, __shfl_down(mxA, off));
        mnB = fminf(mnB, __shfl_down(mnB, off)); mxB = fmaxf(mxB, __shfl_down(mxB, off));
    }
    mnA = __shfl(mnA, 0); mxA = __shfl(mxA, 0);
    mnB = __shfl(mnB, 0); mxB = __shfl(mxB, 0);
    float lo = cl[0], hi = chp[0];
    float mn0 = fminf(fmaxf(mnA, lo), hi), mx0 = fminf(fmaxf(mxA, lo), hi);
    float mn1 = fminf(fmaxf(mnB, lo), hi), mx1 = fminf(fmaxf(mxB, lo), hi);
    float cd0 = (mx0-mn0)*0.125f;
    float cd1 = (mx1-mn1)*0.125f;
    float m0[9], m1[9];
    #pragma unroll
    for (int i=0;i<9;i++){
        m0[i] = __fadd_rn(__fmul_rn((float)i, cd0), mn0);   // match ref: mul then add, no fma
        m1[i] = __fadd_rn(__fmul_rn((float)i, cd1), mn1);
    }
    int g = b*4 + wv;
    int dh, dw; group_off(wv, dh, dw);
    int doff = dh*SROW + dw;
    const float* sp = s + (size_t)b*SBP + SROW + 1;
    float* lhg = lh + wv*2048 + (lane & 31);
    __syncthreads();
    for (int idx = blockIdx.x*64 + lane; idx < NPIX; idx += 32*64){
        int h = idx / HP, w = idx - h*HP;
        const float* p = sp + h*SROW + w;
        float c = p[0];
        float v0 = fminf(fmaxf(c - p[doff],  lo), hi);
        float v1 = fminf(fmaxf(c - p[-doff], lo), hi);
        unsigned b0=0, b1=0;
        #pragma unroll
        for (int i=0;i<8;i++){
            b0 |= (v0>=m0[i] && v0<=m0[i+1]) ? (1u<<i) : 0u;  // boundary values hit 2 bins, like ref
            b1 |= (v1>=m1[i] && v1<=m1[i+1]) ? (1u<<i) : 0u;
        }
        float pr = v0*v1;
        unsigned bb0=b0;
        while (bb0){
            int i = __ffs(bb0)-1; bb0 &= bb0-1;
            unsigned bb1=b1;
            while (bb1){
                int j = __ffs(bb1)-1; bb1 &= bb1-1;
                atomicAdd(&lhg[(i*8+j)*32], pr);
            }
        }
    }
    __syncthreads();
    float acc = 0.f;
    #pragma unroll
    for (int r=0;r<32;r++) acc += lh[(wv*64 + lane)*32 + ((lane + r)&31)];
    atomicAdd(&hist[g*64 + lane], acc);
}

// ---- K45: one block per batch: minmax-reduce, hist-sum, expand+leaky (LDS),
//      weighted LN stats per wave, then w_conv+leaky+w_final fold -> w9 ----
__global__ __launch_bounds__(256) void k45(const float* __restrict__ hist,
                    const float* __restrict__ pmn, const float* __restrict__ pmx,
                    const float* __restrict__ cl, const float* __restrict__ chp,
                    const float* __restrict__ we, const float* __restrict__ be,
                    const float* __restrict__ wc, const float* __restrict__ bc,
                    const float* __restrict__ wf,
                    float* __restrict__ w9g){
    __shared__ float hloc[4*3584];    // 56 KB
    __shared__ float wfl[144];
    __shared__ float wred[4][16];
    __shared__ float gmn[8], gmx[8];
    __shared__ float gstat[8];
    __shared__ float sred[4];
    int b = blockIdx.x, tid = threadIdx.x;
    int wv = tid >> 6, lane = tid & 63;
    if (tid < 144) wfl[tid] = wf[tid];

    // minmax partial reduce (all 8 q) for this batch
    float rmn[8], rmx[8];
    #pragma unroll
    for (int q=0;q<8;q++){ rmn[q]=INFINITY; rmx[q]=-INFINITY; }
    for (int t = tid; t < NT; t += 256){
        const float* pn = pmn + ((size_t)(b*NT + t))*8;
        const float* px = pmx + ((size_t)(b*NT + t))*8;
        #pragma unroll
        for (int q=0;q<8;q++){ rmn[q]=fminf(rmn[q],pn[q]); rmx[q]=fmaxf(rmx[q],px[q]); }
    }
    #pragma unroll
    for (int off=32; off; off>>=1){
        #pragma unroll
        for (int q=0;q<8;q++){
            rmn[q] = fminf(rmn[q], __shfl_down(rmn[q], off));
            rmx[q] = fmaxf(rmx[q], __shfl_down(rmx[q], off));
        }
    }
    if (lane == 0){
        #pragma unroll
        for (int q=0;q<8;q++){ wred[wv][q]=rmn[q]; wred[wv][8+q]=rmx[q]; }
    }
    __syncthreads();
    if (tid < 8)
        gmn[tid] = fminf(fminf(wred[0][tid],wred[1][tid]), fminf(wred[2][tid],wred[3][tid]));
    else if (tid < 16){
        int q = tid-8;
        gmx[q] = fmaxf(fmaxf(wred[0][8+q],wred[1][8+q]), fmaxf(wred[2][8+q],wred[3][8+q]));
    }

    // global hist sum S
    float ps = 0.f;
    for (int t = tid; t < 4096; t += 256) ps += hist[t];
    #pragma unroll
    for (int off=32; off; off>>=1) ps += __shfl_down(ps, off);
    if (lane == 0) sred[wv] = ps;
    __syncthreads();
    float S = sred[0]+sred[1]+sred[2]+sred[3];

    // wave wv: expand + leaky for group g = b*4+wv
    int g = b*4 + wv;
    float lo = cl[0], hi = chp[0];
    float mn0 = fminf(fmaxf(gmn[2*wv  ], lo), hi), mx0 = fminf(fmaxf(gmx[2*wv  ], lo), hi);
    float mn1 = fminf(fmaxf(gmn[2*wv+1], lo), hi), mx1 = fminf(fmaxf(gmx[2*wv+1], lo), hi);
    float lvl0 = __fadd_rn(__fmul_rn(1.0f,(mx0-mn0)*0.125f), mn0);   // measure[:,1,0]
    float lvl1 = __fadd_rn(__fmul_rn(1.0f,(mx1-mn1)*0.125f), mn1);
    for (int e = lane; e < 3584; e += 64){
        int ij = e/56, o = e - ij*56;
        int i = ij>>3, j = ij&7;
        float f0 = __fmul_rn((float)(i+1), lvl0);
        float f1 = __fmul_rn((float)(j+1), lvl1);
        float f2 = hist[g*64+ij] / S;
        float a = f0*we[o*3+0] + f1*we[o*3+1] + f2*we[o*3+2] + be[o];
        hloc[wv*3584 + e] = leaky(a);
    }
    // weighted LN stats (row weight 4, col weight cnt[o]); wave-local
    float pm = 0.f;
    for (int e = lane; e < 3584; e += 64){
        int o = e%56;
        int lo_ = (32*o+6)/7, hi_ = (32*o+31)/7;
        pm += hloc[wv*3584+e] * (float)(4*(hi_-lo_+1));
    }
    #pragma unroll
    for (int off=32; off; off>>=1) pm += __shfl_down(pm, off);
    pm = __shfl(pm, 0);
    float mean = pm * (1.0f/65536.0f);
    float pv = 0.f;
    for (int e = lane; e < 3584; e += 64){
        int o = e%56;
        int lo_ = (32*o+6)/7, hi_ = (32*o+31)/7;
        float d = hloc[wv*3584+e] - mean;
        pv += d*d * (float)(4*(hi_-lo_+1));
    }
    #pragma unroll
    for (int off=32; off; off>>=1) pv += __shfl_down(pv, off);
    pv = __shfl(pv, 0);
    if (lane == 0){
        gstat[wv*2+0] = mean;
        gstat[wv*2+1] = 1.0f / sqrtf(pv * (1.0f/65536.0f) + 1e-5f);
    }
    __syncthreads();

    // LN + w_conv + leaky + vertical/channel fold into w9
    for (int e = tid; e < 3584; e += 256){
        float hn[4];
        #pragma unroll
        for (int k=0;k<4;k++) hn[k] = (hloc[k*3584+e] - gstat[2*k]) * gstat[2*k+1];
        float w9v[9] = {0,0,0,0,0,0,0,0,0};
        #pragma unroll
        for (int c=0;c<16;c++){
            float hv = bc[c];
            #pragma unroll
            for (int k=0;k<4;k++) hv += wc[c*4+k]*hn[k];
            hv = leaky(hv);
            #pragma unroll
            for (int t=0;t<9;t++) w9v[t] += wfl[c*9+t]*hv;
        }
        int r = e/56, sxc = e - r*56;
        float* dst = w9g + (((size_t)b*64 + r)*9)*56 + sxc;
        #pragma unroll
        for (int t=0;t<9;t++) dst[t*56] = w9v[t];
    }
}

// ---- K5: out[b,y,x] = leaky(bf + sum_{dy,dx} w9[b][r(y,dy)][dy*3+dx][sx(x,dx)]) ----
__global__ __launch_bounds__(256) void k5_out(const float* __restrict__ w9g, const float* __restrict__ bf,
                                              float* __restrict__ out){
    int x = threadIdx.x;
    int y = blockIdx.x & 255;
    int b = blockIdx.x >> 8;
    const float* wb = w9g + (size_t)b*64*9*56;
    float acc = bf[0];
    int sxm = ((x-1)*7) >> 5;
    int sx0 = (x*7) >> 5;
    int sxp = ((x+1)*7) >> 5;
    #pragma unroll
    for (int dy=0; dy<3; ++dy){
        int yy = y + dy - 1;
        if ((unsigned)yy >= 256u) continue;
        const float* wr = wb + (((yy>>2)*9) + dy*3)*56;
        if (x >= 1)   acc += wr[0*56 + sxm];
                      acc += wr[1*56 + sx0];
        if (x <= 254) acc += wr[2*56 + sxp];
    }
    out[((size_t)(b*256 + y))*256 + x] = leaky(acc);
}

extern "C" void kernel_launch(void* const* d_in, const int* in_sizes, int n_in,
                              void* d_out, int out_size, void* d_ws, size_t ws_size,
                              hipStream_t stream){
    const float* x  = (const float*)d_in[0];
    const float* cl = (const float*)d_in[1];
    const float* ch = (const float*)d_in[2];
    const float* we = (const float*)d_in[3];
    const float* be = (const float*)d_in[4];
    const float* wc = (const float*)d_in[5];
    const float* bc = (const float*)d_in[6];
    const float* wf = (const float*)d_in[7];
    const float* bf = (const float*)d_in[8];
    float* out = (float*)d_out;

    float* s = (float*)d_ws;                          // 16*SBP floats (zero-padded field)
    size_t off = (size_t)BATCH*SBP;
    float* pmn  = s + off; off += (size_t)BATCH*NT*8;
    float* pmx  = s + off; off += (size_t)BATCH*NT*8;
    float* hist = s + off; off += 4096;
    float* w9g  = s + off; off += (size_t)16*64*9*56;

    k12<<<BATCH*NT, 256, 0, stream>>>(x, s, pmn, pmx, hist);
    k3_hist<<<dim3(32,BATCH), 256, 0, stream>>>(s, cl, ch, pmn, pmx, hist);
    k45<<<BATCH, 256, 0, stream>>>(hist, pmn, pmx, cl, ch, we, be, wc, bc, wf, w9g);
    k5_out<<<16*256, 256, 0, stream>>>(w9g, bf, out);
}